// Round 8
// baseline (155.037 us; speedup 1.0000x reference)
//
#include <hip/hip_runtime.h>
#include <math.h>
#include <stdint.h>

#define K_NN 16
#define NPTS 8192
#define G 32
#define NC (G * G)

// Standard-normal quantiles Phi^-1(i/32), i=1..31, with +/-FLT_MAX sentinels.
// Used BOTH for cell assignment (binary search) and for ring-pruning bounds,
// so binning and geometry are mutually consistent by construction.
static __device__ __constant__ float d_bt[33] = {
    -3.4028235e38f,
    -1.8627318f, -1.5341205f, -1.3180109f, -1.1503494f, -1.0100762f,
    -0.8871466f, -0.7764218f, -0.6744898f, -0.5791322f, -0.4887764f,
    -0.4022501f, -0.3186394f, -0.2372021f, -0.1573107f, -0.0784124f,
     0.0f,
     0.0784124f,  0.1573107f,  0.2372021f,  0.3186394f,  0.4022501f,
     0.4887764f,  0.5791322f,  0.6744898f,  0.7764218f,  0.8871466f,
     1.0100762f,  1.1503494f,  1.3180109f,  1.5341205f,  1.8627318f,
     3.4028235e38f
};

__device__ __forceinline__ int bsearch5(const float* bt, float x) {
    int c = 0;
    c += (x >= bt[c + 16]) ? 16 : 0;
    c += (x >= bt[c + 8])  ? 8  : 0;
    c += (x >= bt[c + 4])  ? 4  : 0;
    c += (x >= bt[c + 2])  ? 2  : 0;
    c += (x >= bt[c + 1])  ? 1  : 0;
    return c;               // in [0, 31]
}

// ---------------------------------------------------------------------------
// kb: grid build. One 1024-thread block: histogram 8192 poly-transformed
// points into 32x32 quantile cells (LDS atomics), Hillis-Steele scan,
// scatter into cell-sorted order (spts = transformed coords, sidx = original
// index). Within-cell order is nondeterministic -- harmless, the packed-key
// insert in kq is order-independent. Also zeroes d_out.
// ---------------------------------------------------------------------------
__global__ __launch_bounds__(1024) void kb_build(const float* __restrict__ ch2,
                                                 const float* __restrict__ M1,
                                                 const float* __restrict__ M2,
                                                 float2* __restrict__ spts,
                                                 int* __restrict__ sidx,
                                                 int* __restrict__ cellStart,
                                                 float* __restrict__ out) {
    __shared__ int hist[NC];
    __shared__ int scn[NC];
    __shared__ float bt[33];
    const int tid = threadIdx.x;
    if (tid == 0) out[0] = 0.0f;
    if (tid < 33) bt[tid] = d_bt[tid];
    hist[tid] = 0;
    __syncthreads();

    const float a0 = M1[0], a1 = M1[1], a2 = M1[2], a3 = M1[3];
    const float b0 = M2[0], b1 = M2[1], b2 = M2[2], b3 = M2[3];

    // phase 1: histogram
    for (int i = tid; i < NPTS; i += 1024) {
        float2 v = ((const float2*)ch2)[i];
        float px = a0 + a1 * v.y + v.x * (a2 + a3 * v.y);
        float py = b0 + b1 * v.y + v.x * (b2 + b3 * v.y);
        int cx = bsearch5(bt, px);
        int cy = bsearch5(bt, py);
        atomicAdd(&hist[cy * G + cx], 1);
    }
    __syncthreads();

    // phase 2: inclusive scan (1024 cells, 1024 threads), then exclusive
    scn[tid] = hist[tid];
    __syncthreads();
    for (int off = 1; off < NC; off <<= 1) {
        int t = scn[tid];
        int u = (tid >= off) ? scn[tid - off] : 0;
        __syncthreads();
        scn[tid] = t + u;
        __syncthreads();
    }
    int excl = scn[tid] - hist[tid];
    cellStart[tid] = excl;
    if (tid == NC - 1) cellStart[NC] = scn[tid];
    __syncthreads();
    hist[tid] = excl;          // reuse as running scatter offsets
    __syncthreads();

    // phase 3: scatter
    for (int i = tid; i < NPTS; i += 1024) {
        float2 v = ((const float2*)ch2)[i];
        float px = a0 + a1 * v.y + v.x * (a2 + a3 * v.y);
        float py = b0 + b1 * v.y + v.x * (b2 + b3 * v.y);
        int cx = bsearch5(bt, px);
        int cy = bsearch5(bt, py);
        int pos = atomicAdd(&hist[cy * G + cx], 1);
        spts[pos] = make_float2(px, py);
        sidx[pos] = i;
    }
}

// ---------------------------------------------------------------------------
// kq: one wave per query. Expand Chebyshev rings of cells around the query's
// cell; per contiguous cell-range, lanes score points (coalesced float2
// gather, L2-resident) and the usual ballot + DPP-insert event loop maintains
// the packed top-16 (trunc-dist | orig-idx -> exact jax tie order, order-
// independent). Stop when kth trunc-dist <= squared margin to the unprocessed
// region (kth is NaN-sentinel while <16 found -> compare fails -> continue).
// ---------------------------------------------------------------------------
__global__ __launch_bounds__(256) void kq_query(const float* __restrict__ ch1,
                                                const float2* __restrict__ spts,
                                                const int* __restrict__ sidx,
                                                const int* __restrict__ cellStart,
                                                int* __restrict__ midx) {
    __shared__ float bt[33];
    const int tid = threadIdx.x;
    if (tid < 33) bt[tid] = d_bt[tid];
    __syncthreads();

    const int lane = tid & 63;
    const int qg = blockIdx.x * 4 + (tid >> 6);
    const float qx = ch1[2 * qg + 0];
    const float qy = ch1[2 * qg + 1];
    const int cx = bsearch5(bt, qx);
    const int cy = bsearch5(bt, qy);

    unsigned key = 0xFFFFFFFFu;    // lanes 0-15: sorted top-16 packed keys
    unsigned kth = 0xFFFFFFFFu;
    unsigned thr = 0xFFFFFFFFu;

#define SCAN_RANGE(ROW, CA, CB)                                               \
    {                                                                         \
        int st = cellStart[(ROW) * G + (CA)];                                 \
        int en = cellStart[(ROW) * G + (CB) + 1];                             \
        for (int base = st; base < en; base += 64) {                          \
            int i = base + lane;                                              \
            unsigned ndb = 0xFFFFFFFFu;                                       \
            int si = 0x1FFF;                                                  \
            if (i < en) {                                                     \
                float2 p = spts[i];                                           \
                si = sidx[i];                                                 \
                float dx = qx - p.x, dy = qy - p.y;                           \
                ndb = __float_as_uint(dx * dx + dy * dy);                     \
            }                                                                 \
            unsigned long long m = __ballot(ndb <= thr);                      \
            while (m) {                                                       \
                int l = __ffsll(m) - 1;                                       \
                unsigned snd = (unsigned)__builtin_amdgcn_readlane((int)ndb, l); \
                unsigned ssi = (unsigned)__builtin_amdgcn_readlane(si, l);    \
                unsigned snk = (snd & 0xFFFFE000u) | ssi;                     \
                if (snk < kth) {                                              \
                    unsigned up = (unsigned)__builtin_amdgcn_update_dpp(      \
                        0, (int)key, 0x111, 0xF, 0xF, false); /* row_shr:1 */ \
                    bool c1 = snk < key;                                      \
                    unsigned nv = (snk < up) ? up : snk;                      \
                    key = c1 ? nv : key;                                      \
                    kth = (unsigned)__builtin_amdgcn_readlane((int)key, 15);  \
                    thr = kth | 0x1FFFu;                                      \
                }                                                             \
                m &= m - 1;                                                   \
                m &= __ballot(ndb <= thr);                                    \
            }                                                                 \
        }                                                                     \
    }

    for (int r = 0; r <= 2 * G; ++r) {
        int rlo = cy - r, rhi = cy + r;
        int clo = max(cx - r, 0), chi = min(cx + r, G - 1);
        if (rlo >= 0) SCAN_RANGE(rlo, clo, chi)
        if (rhi <= G - 1 && r > 0) SCAN_RANGE(rhi, clo, chi)
        int mlo = max(rlo + 1, 0), mhi = min(rhi - 1, G - 1);
        if (cx - r >= 0)
            for (int rr = mlo; rr <= mhi; ++rr) SCAN_RANGE(rr, cx - r, cx - r)
        if (cx + r <= G - 1)
            for (int rr = mlo; rr <= mhi; ++rr) SCAN_RANGE(rr, cx + r, cx + r)

        // stop check: margin = distance from q to unprocessed region
        float Lx = (cx - r <= 0)     ? -3.4028235e38f : bt[cx - r];
        float Rx = (cx + r >= G - 1) ?  3.4028235e38f : bt[cx + r + 1];
        float Ly = (cy - r <= 0)     ? -3.4028235e38f : bt[cy - r];
        float Ry = (cy + r >= G - 1) ?  3.4028235e38f : bt[cy + r + 1];
        float mg = fminf(fminf(qx - Lx, Rx - qx), fminf(qy - Ly, Ry - qy));
        mg = fmaxf(mg, 0.0f);
        float kd = __uint_as_float(kth & 0xFFFFE000u);   // NaN while <16 found
        if (kd <= mg * mg) break;
    }
#undef SCAN_RANGE

    if (lane < K_NN)
        midx[qg * K_NN + lane] = (int)(key & 0x1FFFu);
}

// ---------------------------------------------------------------------------
// k3: scrambled gather + log-sum-exp. One thread per (n,k) pair (131072).
// A[k,n] = midx[(k*(N/K) + n/K)*K + (n%K)]; distance recomputed exactly with
// the polynomial applied on the fly. midx holds ORIGINAL ch2 indices.
// ---------------------------------------------------------------------------
__global__ __launch_bounds__(1024) void k3_final(const float* __restrict__ ch1,
                                                 const float* __restrict__ ch2,
                                                 const float* __restrict__ M1,
                                                 const float* __restrict__ M2,
                                                 const int* __restrict__ midx,
                                                 float* __restrict__ out, int N) {
    const float a0 = M1[0], a1 = M1[1], a2 = M1[2], a3 = M1[3];
    const float b0 = M2[0], b1 = M2[1], b2 = M2[2], b3 = M2[3];

    int t = blockIdx.x * 1024 + threadIdx.x;  // [0, N*K)
    int n = t >> 4;
    int k = t & 15;
    int g = n >> 4;
    int r = n & 15;

    int j = k * (N / K_NN) + g;
    int a = midx[j * K_NN + r];
    float2 cp = ((const float2*)ch2)[a];
    float cx = a0 + a1 * cp.y + cp.x * (a2 + a3 * cp.y);
    float cy = b0 + b1 * cp.y + cp.x * (b2 + b3 * cp.y);
    float dx = ch1[2 * n + 0] - cx;
    float dy = ch1[2 * n + 1] - cy;
    float term = expf(-(dx * dx + dy * dy) * (1.0f / 4.5f));

#pragma unroll
    for (int off = 8; off; off >>= 1) term += __shfl_down(term, off, 16);

    float v = 0.0f;
    if (k == 0) {
        float expD = term / (float)N;
        v = (expD != 0.0f) ? logf(expD) : 0.0f;
    }
#pragma unroll
    for (int off = 32; off; off >>= 1) v += __shfl_down(v, off, 64);

    __shared__ float red[16];
    int lane = threadIdx.x & 63;
    int wv = threadIdx.x >> 6;
    if (lane == 0) red[wv] = v;
    __syncthreads();
    if (threadIdx.x == 0) {
        float s = 0.0f;
#pragma unroll
        for (int i = 0; i < 16; ++i) s += red[i];
        atomicAdd(out, -s);
    }
}

// ---------------------------------------------------------------------------
extern "C" void kernel_launch(void* const* d_in, const int* in_sizes, int n_in,
                              void* d_out, int out_size, void* d_ws, size_t ws_size,
                              hipStream_t stream) {
    const float* ch1 = (const float*)d_in[0];
    const float* ch2 = (const float*)d_in[1];
    const float* M1  = (const float*)d_in[2];
    const float* M2  = (const float*)d_in[3];
    float* out = (float*)d_out;
    const int N = in_sizes[0] / 2;   // 8192

    char* ws = (char*)d_ws;
    float2* spts     = (float2*)ws;                          //  64 KB
    int*    midx     = (int*)(ws + 65536);                   // 512 KB
    int*    sidx     = (int*)(ws + 65536 + 524288);          //  32 KB
    int*    cellStart= (int*)(ws + 65536 + 524288 + 32768);  // ~4.1 KB

    kb_build<<<1, 1024, 0, stream>>>(ch2, M1, M2, spts, sidx, cellStart, out);

    kq_query<<<N / 4, 256, 0, stream>>>(ch1, spts, sidx, cellStart, midx);

    k3_final<<<(N * K_NN) / 1024, 1024, 0, stream>>>(ch1, ch2, M1, M2, midx, out, N);
}

// Round 9
// 90.929 us; speedup vs baseline: 1.7050x; 1.7050x over previous
//
#include <hip/hip_runtime.h>
#include <math.h>
#include <stdint.h>

#define K_NN 16
#define NPTS 8192
#define HALF (NPTS / 2)     // 4096 points staged per pass (32 KB LDS)
#define STEPS (HALF / 256)  // 16 steps/pass, 256 candidates/step (4/lane)
#define WPB 16              // waves (= queries) per block; block = 1024 threads

// ---------------------------------------------------------------------------
// k1: wave-cooperative KNN, one wave per query, candidate set in LDS in two
// 32 KB passes (2 blocks/CU -> 32 waves/CU = 100% occupancy).
// Top-16 = lane-distributed sorted packed keys (dist_bits & ~0x1FFF) | idx in
// lanes 0-15. Per step: 4 candidates/lane via 2x ds_read_b128, eager VALU
// packing, 4 ballots vs wave-uniform thr. Event loop is MINIMAL: readlane +
// DPP row_shr:1 insert (self-rejecting, always exact) -- kth/thr refresh is
// DEFERRED to once per step (stale thr only over-admits; termination via
// m &= m-1 on a static ballot). Step 0 warm-starts thr from 16 group-minima
// (16 distinct candidates -> certified >= step-0 16th order stat, so no
// qualifying candidate is missed). Packing = exact jax top_k tie order
// modulo 2^-13 dist truncation; k3 recomputes exact distances.
// ---------------------------------------------------------------------------
__global__ __launch_bounds__(1024) void k1_knn(const float* __restrict__ ch1,
                                               const float* __restrict__ ch2,
                                               const float* __restrict__ M1,
                                               const float* __restrict__ M2,
                                               int* __restrict__ midx,
                                               float* __restrict__ out) {
    __shared__ float2 sh[HALF];        // 32 KB: half the transformed ch2

    const int tid  = threadIdx.x;
    const int lane = tid & 63;
    const int w    = tid >> 6;
    const int qg   = blockIdx.x * WPB + w;

    if (blockIdx.x == 0 && tid == 0) out[0] = 0.0f;   // k3 atomics start from 0

    const float q0 = ch1[2 * qg + 0];
    const float q1 = ch1[2 * qg + 1];

    const float a0 = M1[0], a1 = M1[1], a2 = M1[2], a3 = M1[3];
    const float b0 = M2[0], b1 = M2[1], b2 = M2[2], b3 = M2[3];

    const float4* __restrict__ g4 = (const float4*)ch2;

    unsigned key = 0xFFFFFFFFu;        // lanes 0-15: sorted top-16 packed keys
    unsigned thr = 0xFFFFFFFFu;        // ballot threshold (kth | 0x1FFF)

#define INSERT_EVENTS(MV, NKV)                                                 \
    while (MV) {                                                               \
        int l = __ffsll(MV) - 1;                                               \
        MV &= MV - 1;                                                          \
        unsigned snk = (unsigned)__builtin_amdgcn_readlane((int)(NKV), l);     \
        unsigned up = (unsigned)__builtin_amdgcn_update_dpp(                   \
            0, (int)key, 0x111, 0xF, 0xF, false);   /* row_shr:1 */            \
        bool c1 = snk < key;                                                   \
        unsigned nv = (snk < up) ? up : snk;                                   \
        key = c1 ? nv : key;                                                   \
    }

    for (int pass = 0; pass < 2; ++pass) {
        __syncthreads();               // protect sh against previous pass scan
        // stage 4096 points (poly fused): 2048 float4 / 1024 threads
#pragma unroll
        for (int e = 0; e < (HALF / 2) / 1024; ++e) {
            float4 v = g4[pass * (HALF / 2) + e * 1024 + tid];
            float px0 = a0 + a1 * v.y + v.x * (a2 + a3 * v.y);
            float py0 = b0 + b1 * v.y + v.x * (b2 + b3 * v.y);
            float px1 = a0 + a1 * v.w + v.z * (a2 + a3 * v.w);
            float py1 = b0 + b1 * v.w + v.z * (b2 + b3 * v.w);
            ((float4*)sh)[e * 1024 + tid] = make_float4(px0, py0, px1, py1);
        }
        __syncthreads();

        const float4* s4 = (const float4*)sh;
        float4 ca = s4[lane];                       // prefetch step 0
        float4 cb = s4[64 + lane];

        for (int t = 0; t < STEPS; ++t) {
            int tn = (t + 1) & (STEPS - 1);
            float4 na = s4[tn * 128 + lane];        // prefetch next (wraps)
            float4 nb = s4[tn * 128 + 64 + lane];

            // candidate global indices: base, base+1, base+128, base+129
            const int base = pass * HALF + t * 256 + 2 * lane;

            float dx0 = q0 - ca.x, dy0 = q1 - ca.y;
            float dx1 = q0 - ca.z, dy1 = q1 - ca.w;
            float dx2 = q0 - cb.x, dy2 = q1 - cb.y;
            float dx3 = q0 - cb.z, dy3 = q1 - cb.w;
            unsigned u0 = __float_as_uint(dx0 * dx0 + dy0 * dy0);
            unsigned u1 = __float_as_uint(dx1 * dx1 + dy1 * dy1);
            unsigned u2 = __float_as_uint(dx2 * dx2 + dy2 * dy2);
            unsigned u3 = __float_as_uint(dx3 * dx3 + dy3 * dy3);

            if (pass == 0 && t == 0) {
                // warm start: 16 group-minima (lanes {4i..4i+3} x 4 cands =
                // 16 distinct candidates); wave-max of them bounds the
                // step-0 16th order statistic from above.
                unsigned mn = min(min(u0, u1), min(u2, u3));
                mn = min(mn, (unsigned)__shfl_xor((int)mn, 1, 64));
                mn = min(mn, (unsigned)__shfl_xor((int)mn, 2, 64));
                unsigned mx = mn;
                mx = max(mx, (unsigned)__shfl_xor((int)mx, 4, 64));
                mx = max(mx, (unsigned)__shfl_xor((int)mx, 8, 64));
                mx = max(mx, (unsigned)__shfl_xor((int)mx, 16, 64));
                mx = max(mx, (unsigned)__shfl_xor((int)mx, 32, 64));
                thr = mx | 0x1FFFu;
            }

            unsigned nk0 = (u0 & 0xFFFFE000u) | (unsigned)base;
            unsigned nk1 = (u1 & 0xFFFFE000u) | (unsigned)(base + 1);
            unsigned nk2 = (u2 & 0xFFFFE000u) | (unsigned)(base + 128);
            unsigned nk3 = (u3 & 0xFFFFE000u) | (unsigned)(base + 129);

            unsigned long long m0 = __ballot(u0 <= thr);
            unsigned long long m1 = __ballot(u1 <= thr);
            unsigned long long m2 = __ballot(u2 <= thr);
            unsigned long long m3 = __ballot(u3 <= thr);

            INSERT_EVENTS(m0, nk0)
            INSERT_EVENTS(m1, nk1)
            INSERT_EVENTS(m2, nk2)
            INSERT_EVENTS(m3, nk3)

            // deferred refresh: once per step
            thr = (unsigned)__builtin_amdgcn_readlane((int)key, 15) | 0x1FFFu;

            ca = na;
            cb = nb;
        }
    }
#undef INSERT_EVENTS

    if (lane < K_NN)
        midx[qg * K_NN + lane] = (int)(key & 0x1FFFu);
}

// ---------------------------------------------------------------------------
// k3: scrambled gather + log-sum-exp. One thread per (n,k) pair (131072).
// A[k,n] = midx[(k*(N/K) + n/K)*K + (n%K)]; distance recomputed exactly with
// the polynomial applied on the fly. 1024-thread blocks -> 128 atomics total.
// ---------------------------------------------------------------------------
__global__ __launch_bounds__(1024) void k3_final(const float* __restrict__ ch1,
                                                 const float* __restrict__ ch2,
                                                 const float* __restrict__ M1,
                                                 const float* __restrict__ M2,
                                                 const int* __restrict__ midx,
                                                 float* __restrict__ out, int N) {
    const float a0 = M1[0], a1 = M1[1], a2 = M1[2], a3 = M1[3];
    const float b0 = M2[0], b1 = M2[1], b2 = M2[2], b3 = M2[3];

    int t = blockIdx.x * 1024 + threadIdx.x;  // [0, N*K)
    int n = t >> 4;
    int k = t & 15;
    int g = n >> 4;          // n / K
    int r = n & 15;          // n % K

    int j = k * (N / K_NN) + g;
    int a = midx[j * K_NN + r];
    float2 cp = ((const float2*)ch2)[a];
    float cx = a0 + a1 * cp.y + cp.x * (a2 + a3 * cp.y);
    float cy = b0 + b1 * cp.y + cp.x * (b2 + b3 * cp.y);
    float dx = ch1[2 * n + 0] - cx;
    float dy = ch1[2 * n + 1] - cy;
    float term = expf(-(dx * dx + dy * dy) * (1.0f / 4.5f));

    // sum over k within each 16-lane group
#pragma unroll
    for (int off = 8; off; off >>= 1) term += __shfl_down(term, off, 16);

    float v = 0.0f;
    if (k == 0) {
        float expD = term / (float)N;
        v = (expD != 0.0f) ? logf(expD) : 0.0f;
    }
#pragma unroll
    for (int off = 32; off; off >>= 1) v += __shfl_down(v, off, 64);

    __shared__ float red[16];
    int lane = threadIdx.x & 63;
    int wv = threadIdx.x >> 6;
    if (lane == 0) red[wv] = v;
    __syncthreads();
    if (threadIdx.x == 0) {
        float s = 0.0f;
#pragma unroll
        for (int i = 0; i < 16; ++i) s += red[i];
        atomicAdd(out, -s);
    }
}

// ---------------------------------------------------------------------------
extern "C" void kernel_launch(void* const* d_in, const int* in_sizes, int n_in,
                              void* d_out, int out_size, void* d_ws, size_t ws_size,
                              hipStream_t stream) {
    const float* ch1 = (const float*)d_in[0];
    const float* ch2 = (const float*)d_in[1];
    const float* M1  = (const float*)d_in[2];
    const float* M2  = (const float*)d_in[3];
    float* out = (float*)d_out;
    const int N = in_sizes[0] / 2;   // 8192

    int* midx = (int*)d_ws;          // 512 KB

    k1_knn<<<N / WPB, 1024, 0, stream>>>(ch1, ch2, M1, M2, midx, out);

    k3_final<<<(N * K_NN) / 1024, 1024, 0, stream>>>(ch1, ch2, M1, M2, midx, out, N);
}